// Round 1
// baseline (78.931 us; speedup 1.0000x reference)
//
#include <hip/hip_runtime.h>

// out[n,i,h,j] = x[n,h,j]*w1 + (b - x[n,h,idx(i,j)])*w2
// idx(i,j) = j if j < i else j - i
// B=4, H=256, W=256; out shape (B, W, H, W) = 4*256^3 f32 elements.

__global__ __launch_bounds__(256) void overlap_kernel(
    const float* __restrict__ x,
    const float* __restrict__ bp,
    const float* __restrict__ w1p,
    const float* __restrict__ w2p,
    float* __restrict__ out,
    int total4) {
  const float bb = bp[0];
  const float w1 = w1p[0];
  const float w2 = w2p[0];

  int tid = blockIdx.x * blockDim.x + threadIdx.x;
  int stride = gridDim.x * blockDim.x;

  for (int f = tid; f < total4; f += stride) {
    // flat element index = f*4 = ((n*256 + i)*256 + h)*256 + j
    int j0 = (f & 63) << 2;        // j in [0,256), 4-aligned
    int h  = (f >> 6) & 255;
    int i  = (f >> 14) & 255;
    int n  = f >> 22;

    const float* __restrict__ xrow = x + (((n << 8) + h) << 8);  // x[n][h][*]

    float4 xv = *reinterpret_cast<const float4*>(xrow + j0);

    int j1 = j0 + 1, j2 = j0 + 2, j3 = j0 + 3;
    float t0 = xrow[j0 < i ? j0 : j0 - i];
    float t1 = xrow[j1 < i ? j1 : j1 - i];
    float t2 = xrow[j2 < i ? j2 : j2 - i];
    float t3 = xrow[j3 < i ? j3 : j3 - i];

    float4 o;
    o.x = xv.x * w1 + (bb - t0) * w2;
    o.y = xv.y * w1 + (bb - t1) * w2;
    o.z = xv.z * w1 + (bb - t2) * w2;
    o.w = xv.w * w1 + (bb - t3) * w2;

    *reinterpret_cast<float4*>(out + ((size_t)f << 2)) = o;
  }
}

extern "C" void kernel_launch(void* const* d_in, const int* in_sizes, int n_in,
                              void* d_out, int out_size, void* d_ws, size_t ws_size,
                              hipStream_t stream) {
  const float* x  = (const float*)d_in[0];
  const float* b  = (const float*)d_in[1];
  const float* w1 = (const float*)d_in[2];
  const float* w2 = (const float*)d_in[3];
  float* out = (float*)d_out;

  // out_size = 4*256*256*256 = 67108864; total4 = 16777216 float4 stores
  int total4 = out_size >> 2;
  int block = 256;
  int grid = 2048;  // grid-stride; 256 CU * 8 blocks/CU
  overlap_kernel<<<grid, block, 0, stream>>>(x, b, w1, w2, out, total4);
}

// Round 2
// 47.310 us; speedup vs baseline: 1.6684x; 1.6684x over previous
//
#include <hip/hip_runtime.h>

// out[n,i,h,j] = x[n,h,j]*w1 + (b - x[n,h,idx(i,j)])*w2
// idx(i,j) = j if j < i else j - i
// B=4, H=256, W=256; out shape (B, W=i, H=h, W=j) = 4*256^3 f32.
//
// Wave-level structure: lane l holds a = xrow[4l..4l+3] (full row per wave,
// in registers). The gather row for shift i is concat(xrow[0:i], xrow[0:256-i])
// — reconstructed per i via cross-lane shuffles (funnel shift by i), so the
// hot loop has ZERO global loads: just shfl + VALU + one float4 store.

__global__ __launch_bounds__(256) void overlap_kernel(
    const float* __restrict__ x,
    const float* __restrict__ bp,
    const float* __restrict__ w1p,
    const float* __restrict__ w2p,
    float* __restrict__ out) {
  const float bb = bp[0];
  const float w1 = w1p[0];
  const float w2 = w2p[0];

  int tid  = blockIdx.x * 256 + threadIdx.x;  // 2^19 threads total
  int lane = threadIdx.x & 63;
  int j0   = lane << 2;
  int h    = (tid >> 6) & 255;   // wave-uniform
  int i0   = (tid >> 14) & 31;   // block-dependent, wave-uniform

  #pragma unroll
  for (int nn = 0; nn < 4; ++nn) {
    const float* __restrict__ xrow = x + (((nn << 8) + h) << 8);
    float4 a = *reinterpret_cast<const float4*>(xrow + j0);  // aligned, once

    #pragma unroll
    for (int ii = 0; ii < 8; ++ii) {
      int i = i0 + (ii << 5);          // wave-uniform shift
      int q = i >> 2;                  // float4-granular shift
      int r = i & 3;                   // sub-float4 shift
      int srcA = lane - q;             // negative -> wraps; value unused then
      int srcB = srcA - 1;

      float Ax = __shfl(a.x, srcA, 64);
      float Ay = __shfl(a.y, srcA, 64);
      float Az = __shfl(a.z, srcA, 64);
      float Aw = __shfl(a.w, srcA, 64);
      float Bx = __shfl(a.x, srcB, 64);
      float By = __shfl(a.y, srcB, 64);
      float Bz = __shfl(a.z, srcB, 64);
      float Bw = __shfl(a.w, srcB, 64);
      (void)Bx;

      // shifted row s[k] = xrow[j0+k-i] (valid where j0+k >= i)
      float s0, s1, s2, s3;
      if (r == 0)      { s0 = Ax; s1 = Ay; s2 = Az; s3 = Aw; }
      else if (r == 1) { s0 = Bw; s1 = Ax; s2 = Ay; s3 = Az; }
      else if (r == 2) { s0 = Bz; s1 = Bw; s2 = Ax; s3 = Ay; }
      else             { s0 = By; s1 = Bz; s2 = Bw; s3 = Ax; }

      // t[k] = xrow[j] if j < i else s[k]
      float t0 = (j0 + 0 < i) ? a.x : s0;
      float t1 = (j0 + 1 < i) ? a.y : s1;
      float t2 = (j0 + 2 < i) ? a.z : s2;
      float t3 = (j0 + 3 < i) ? a.w : s3;

      float4 o;
      o.x = a.x * w1 + (bb - t0) * w2;
      o.y = a.y * w1 + (bb - t1) * w2;
      o.z = a.z * w1 + (bb - t2) * w2;
      o.w = a.w * w1 + (bb - t3) * w2;

      // flat float4 index: (((n*256 + i)*256 + h)*256 + j0) / 4
      size_t f4 = (((size_t)(((nn << 8) + i) << 8) + h) << 6) + lane;
      reinterpret_cast<float4*>(out)[f4] = o;
    }
  }
}

extern "C" void kernel_launch(void* const* d_in, const int* in_sizes, int n_in,
                              void* d_out, int out_size, void* d_ws, size_t ws_size,
                              hipStream_t stream) {
  const float* x  = (const float*)d_in[0];
  const float* b  = (const float*)d_in[1];
  const float* w1 = (const float*)d_in[2];
  const float* w2 = (const float*)d_in[3];
  float* out = (float*)d_out;

  // Each thread writes 32 float4 = 128 floats. out_size = 4*256^3 = 2^26.
  int blocks = out_size / (256 * 128);  // = 2048
  overlap_kernel<<<blocks, 256, 0, stream>>>(x, b, w1, w2, out);
}

// Round 3
// 46.512 us; speedup vs baseline: 1.6970x; 1.0172x over previous
//
#include <hip/hip_runtime.h>

// out[n,i,h,j] = x[n,h,j]*w1 + (b - x[n,h,idx(i,j)])*w2
// idx(i,j) = j if j < i else j - i
// B=4, H=256, W=256; out shape (B, W=i, H=h, W=j) = 4*256^3 f32.
//
// Block owns fixed (n, i, h-chunk): i-dependent shuffle setup (q, r, srcA/B,
// compare masks) hoisted out of the loop entirely (r-path chosen once, 4
// bpermutes/iter instead of 8). Inner loop walks 8 consecutive h rows per
// wave -> per-wave 8 KB contiguous stores, per-block 32 KB, and consecutive
// blocks write consecutive chunks: a linear streaming write sweep (same
// pattern as the 7 TB/s fillBuffer). x row reloads are L2 hits (x = 1 MB).

template <int R>
__device__ __forceinline__ void run_rows(
    const float4* __restrict__ xin,   // = (float4*)xrow_base + lane
    float4* __restrict__ oout,        // = out4 base + lane
    int srcA, int srcB,
    bool c0, bool c1, bool c2, bool c3,
    float w1, float w2, float bb) {
  #pragma unroll
  for (int it = 0; it < 8; ++it) {
    float4 a = xin[it * 64];  // next h row, coalesced 1 KB, L2-hit

    float s0, s1, s2, s3;
    if constexpr (R == 0) {
      s0 = __shfl(a.x, srcA, 64); s1 = __shfl(a.y, srcA, 64);
      s2 = __shfl(a.z, srcA, 64); s3 = __shfl(a.w, srcA, 64);
    } else if constexpr (R == 1) {
      s0 = __shfl(a.w, srcB, 64); s1 = __shfl(a.x, srcA, 64);
      s2 = __shfl(a.y, srcA, 64); s3 = __shfl(a.z, srcA, 64);
    } else if constexpr (R == 2) {
      s0 = __shfl(a.z, srcB, 64); s1 = __shfl(a.w, srcB, 64);
      s2 = __shfl(a.x, srcA, 64); s3 = __shfl(a.y, srcA, 64);
    } else {
      s0 = __shfl(a.y, srcB, 64); s1 = __shfl(a.z, srcB, 64);
      s2 = __shfl(a.w, srcB, 64); s3 = __shfl(a.x, srcA, 64);
    }

    float t0 = c0 ? a.x : s0;
    float t1 = c1 ? a.y : s1;
    float t2 = c2 ? a.z : s2;
    float t3 = c3 ? a.w : s3;

    float4 o;
    o.x = a.x * w1 + (bb - t0) * w2;
    o.y = a.y * w1 + (bb - t1) * w2;
    o.z = a.z * w1 + (bb - t2) * w2;
    o.w = a.w * w1 + (bb - t3) * w2;

    oout[it * 64] = o;
  }
}

__global__ __launch_bounds__(256) void overlap_kernel(
    const float* __restrict__ x,
    const float* __restrict__ bp,
    const float* __restrict__ w1p,
    const float* __restrict__ w2p,
    float* __restrict__ out) {
  const float bb = bp[0];
  const float w1 = w1p[0];
  const float w2 = w2p[0];

  // grid = 4 * 256 * 8 = 8192 blocks; bl = ((n*256 + i)*8 + hc)
  int bl = blockIdx.x;
  int hc = bl & 7;
  int i  = (bl >> 3) & 255;   // block-uniform shift
  int n  = bl >> 11;

  int lane  = threadIdx.x & 63;
  int w     = threadIdx.x >> 6;            // wave id 0..3
  int hbase = (hc << 5) + (w << 3);        // 8 consecutive h rows per wave
  int j0    = lane << 2;

  int q = i >> 2;
  int r = i & 3;
  int srcA = lane - q;
  int srcB = srcA - 1;

  bool c0 = (j0 + 0) < i;
  bool c1 = (j0 + 1) < i;
  bool c2 = (j0 + 2) < i;
  bool c3 = (j0 + 3) < i;

  const float4* xin = reinterpret_cast<const float4*>(x + (n << 16) + (hbase << 8)) + lane;
  float4* oout = reinterpret_cast<float4*>(out) +
                 (((n << 8) + i) << 14) + (hbase << 6) + lane;

  switch (r) {  // block-uniform, no divergence
    case 0: run_rows<0>(xin, oout, srcA, srcB, c0, c1, c2, c3, w1, w2, bb); break;
    case 1: run_rows<1>(xin, oout, srcA, srcB, c0, c1, c2, c3, w1, w2, bb); break;
    case 2: run_rows<2>(xin, oout, srcA, srcB, c0, c1, c2, c3, w1, w2, bb); break;
    default: run_rows<3>(xin, oout, srcA, srcB, c0, c1, c2, c3, w1, w2, bb); break;
  }
}

extern "C" void kernel_launch(void* const* d_in, const int* in_sizes, int n_in,
                              void* d_out, int out_size, void* d_ws, size_t ws_size,
                              hipStream_t stream) {
  const float* x  = (const float*)d_in[0];
  const float* b  = (const float*)d_in[1];
  const float* w1 = (const float*)d_in[2];
  const float* w2 = (const float*)d_in[3];
  float* out = (float*)d_out;

  // 8192 blocks x 256 threads; each wave writes 8 contiguous 1 KB rows.
  overlap_kernel<<<8192, 256, 0, stream>>>(x, b, w1, w2, out);
}